// Round 21
// baseline (37.804 us; speedup 1.0000x reference)
//
#include <hip/hip_runtime.h>
#include <hip/hip_bf16.h>

// Depth-4 path signature, C=10, L=64, B=2048 — MFMA formulation (R21).
// Closed form (validated R8-R20, absmax 5.25 vs thr 12.16):
//   P_t = exclusive prefix of dx;  R_t[l] = S1[l] - P_{t+1}[l]
//   per (i,j): s2 = prefix_t of z_t, z=(P+di/2)dj; u2=(P+di/4)dj/3+s2,
//   v2=(P+di/3)dj/2+s2
//   S4[ij,kl] = sum_t v2_t*(dx_t[k]*R_t[l]) + sum_t u2_t*(dx_t[k]*dx_t[l]/2)
//   S3[ij,k]  = sum_t v2_t*dx_t[k]
// Structure = R20 (best, 35.9us): 512thr/1elem/8waves, V2->Ab U2->Ub B->Bb,
// two K=64 GEMM passes (1 rt-strip per wave), transposed-C f2 epilogue,
// LDS 45.3KB -> 3 blocks/CU, __launch_bounds__(512,6).
// R21 delta: A-build parallelized 8 lanes/row (was 1 lane/row on 2 waves,
// ~640 VALU insts critical path while 6 waves idled). Per row: 8 chunks of
// 8 steps; pointwise z/bu/bv; 3-step __shfl_up(.,d,8) exclusive scan of
// chunk sums; in-lane serial finalize. All 512 lanes busy, 2 iterations.
// S2 sum reassociated (fp32 tree) — feeds bf16 quantization, immaterial.

typedef short short8 __attribute__((ext_vector_type(8)));
typedef float f2 __attribute__((ext_vector_type(2)));
typedef float f32x4 __attribute__((ext_vector_type(4)));
typedef unsigned int uint4v __attribute__((ext_vector_type(4)));

constexpr int C = 10, L = 64, T = 63;          // T = L-1 steps
constexpr int OUTSZ = 10 + 100 + 1000 + 10000; // 11110
constexpr int DXP = 11;                        // dx/P row stride (fp32 words, odd)
constexpr int KS = 64;                         // per-pass row stride in shorts (128B)

__device__ __forceinline__ unsigned packbf(float lo, float hi) {  // v_cvt_pk_bf16_f32
  union { __hip_bfloat162 h; unsigned u; } cv;
  cv.h = __float22bfloat162_rn(make_float2(lo, hi));
  return cv.u;
}
__device__ __forceinline__ int swz(int row, int k) {  // short idx, 16B-granule XOR
  return row * KS + ((((k >> 3) ^ (row & 7)) << 3) | (k & 7));
}

__global__ __launch_bounds__(512, 6) void sig4_kernel(
    const float* __restrict__ x, float* __restrict__ out)
{
  __shared__ __align__(16) unsigned char smem_raw[45280];
  unsigned short* Ab = (unsigned short*)smem_raw;            // V2: 100*64 sh = 12800B
  unsigned short* Ub = (unsigned short*)(smem_raw + 12800);  // U2: 100*64 sh = 12800B
  unsigned short* Bb = (unsigned short*)(smem_raw + 25600);  // 110*64 sh = 14080B
  float* dxs = (float*)(smem_raw + 39680);                   // 63*11 f = 2772B
  float* Ps  = (float*)(smem_raw + 42452);                   // 64*11 f = 2816B

  const int t = threadIdx.x;
  const int w = t >> 6, lane = t & 63;
  const float* __restrict__ xb = x + (size_t)blockIdx.x * (C * L);
  float* __restrict__ ob = out + (size_t)blockIdx.x * OUTSZ;

  // ---- phase A: dx direct from global (xb is 2.5KB, L1/L2-resident) ----
  for (int i = t; i < T * C; i += 512) {
    int c = i / T, s = i - c * T;
    dxs[s * DXP + c] = xb[c * L + s + 1] - xb[c * L + s];
  }
  __syncthreads();
  for (int c = w; c < C; c += 8) {   // exclusive prefix P, one channel/wave
    float v = (lane > 0) ? dxs[(lane - 1) * DXP + c] : 0.f;
    #pragma unroll
    for (int d = 1; d < 64; d <<= 1) {
      float y = __shfl_up(v, d);
      if (lane >= d) v += y;
    }
    Ps[lane * DXP + c] = v;   // P[t][c] = sum_{s<t} dx_s[c]; P[63] = S1
  }
  __syncthreads();

  // ---- build: A (8 lanes/row, all waves) then B0 (all lanes) ----
  const int g = lane & 7;            // chunk index within row
  #pragma unroll 1
  for (int it = 0; it < 2; ++it) {
    const int row = it * 64 + w * 8 + (lane >> 3);
    if (row < 100) {
      const int i_ = row / 10, j_ = row - (row / 10) * 10;
      float z[8], bu[8], bv[8];
      #pragma unroll
      for (int e = 0; e < 8; ++e) {  // pointwise, ILP-friendly
        const int s = g * 8 + e;
        if (s < T) {
          float di = dxs[s * DXP + i_];
          float dj = dxs[s * DXP + j_];
          float p  = Ps[s * DXP + i_];
          bu[e] = fmaf(di, 0.25f, p) * (dj * (1.f / 3.f));
          bv[e] = fmaf(di, (1.f / 3.f), p) * (dj * 0.5f);
          z[e]  = fmaf(di, 0.5f, p) * dj;
        } else { bu[e] = 0.f; bv[e] = 0.f; z[e] = 0.f; }
      }
      float zsum = ((z[0] + z[1]) + (z[2] + z[3])) +
                   ((z[4] + z[5]) + (z[6] + z[7]));
      float a = zsum;                // 3-step exclusive scan over 8 chunks
      #pragma unroll
      for (int d = 1; d < 8; d <<= 1) {
        float y = __shfl_up(a, d, 8);
        if (g >= d) a += y;
      }
      float s2 = a - zsum;           // chunk base (exclusive)
      float u2v[8], v2v[8];
      #pragma unroll
      for (int e = 0; e < 8; ++e) {  // in-lane serial finalize
        u2v[e] = bu[e] + s2;
        v2v[e] = bv[e] + s2;
        s2 += z[e];
      }
      uint4v vp, up;
      #pragma unroll
      for (int q = 0; q < 4; ++q) {
        vp[q] = packbf(v2v[2 * q], v2v[2 * q + 1]);
        up[q] = packbf(u2v[2 * q], u2v[2 * q + 1]);
      }
      *(uint4v*)&Ab[swz(row, g * 8)] = vp;
      *(uint4v*)&Ub[swz(row, g * 8)] = up;
      if (g == 7) ob[10 + row] = s2;            // S2 (fp32, chunk-tree sum)
    }
  }
  if (t < 10) ob[t] = Ps[63 * DXP + t];         // S1

  for (int task = t; task < 110 * 8; task += 512) {   // B0 = [dx ox R | dx]
    const int col = task >> 3, ch = task & 7;
    float b1v[8];
    if (col < 100) {
      const int k2 = col / 10, l2 = col - (col / 10) * 10;
      const float S1l = Ps[63 * DXP + l2];
      #pragma unroll
      for (int ee = 0; ee < 8; ++ee) {
        const int kk = ch * 8 + ee;
        b1v[ee] = (kk < T)
            ? dxs[kk * DXP + k2] * (S1l - Ps[(kk + 1) * DXP + l2]) : 0.f;
      }
    } else {
      const int c2 = col - 100;
      #pragma unroll
      for (int ee = 0; ee < 8; ++ee) {
        const int kk = ch * 8 + ee;
        b1v[ee] = (kk < T) ? dxs[kk * DXP + c2] : 0.f;
      }
    }
    uint4v pk;
    #pragma unroll
    for (int qq = 0; qq < 4; ++qq) pk[qq] = packbf(b1v[2 * qq], b1v[2 * qq + 1]);
    *(uint4v*)&Bb[swz(col, ch * 8)] = pk;
  }
  __syncthreads();

  const int lm = lane & 15, lg = lane >> 4;
  f32x4 acc[7];
  #pragma unroll
  for (int ct = 0; ct < 7; ++ct) acc[ct] = f32x4{0.f, 0.f, 0.f, 0.f};

  // ---- GEMM pass 0: one rt-strip per wave (waves 0..6), A=V2 ----
  if (w < 7) {
    const int arow = w * 16 + lm;
    short8 a0 = (arow < 100) ? *(const short8*)&Ab[swz(arow, lg * 8)]
                             : short8{0, 0, 0, 0, 0, 0, 0, 0};
    short8 a1 = (arow < 100) ? *(const short8*)&Ab[swz(arow, 32 + lg * 8)]
                             : short8{0, 0, 0, 0, 0, 0, 0, 0};
    #pragma unroll
    for (int ct = 0; ct < 7; ++ct) {
      const int bcol = ct * 16 + lm;
      short8 b0 = (bcol < 110) ? *(const short8*)&Bb[swz(bcol, lg * 8)]
                               : short8{0, 0, 0, 0, 0, 0, 0, 0};
      short8 b1 = (bcol < 110) ? *(const short8*)&Bb[swz(bcol, 32 + lg * 8)]
                               : short8{0, 0, 0, 0, 0, 0, 0, 0};
      acc[ct] = __builtin_amdgcn_mfma_f32_16x16x32_bf16(b0, a0, acc[ct], 0, 0, 0);
      acc[ct] = __builtin_amdgcn_mfma_f32_16x16x32_bf16(b1, a1, acc[ct], 0, 0, 0);
    }
  }
  __syncthreads();

  // ---- build B1 = [dx ox dx /2 | 0] on ALL 512 lanes ----
  for (int task = t; task < 110 * 8; task += 512) {
    const int col = task >> 3, ch = task & 7;
    float b2v[8] = {0.f, 0.f, 0.f, 0.f, 0.f, 0.f, 0.f, 0.f};
    if (col < 100) {
      const int k2 = col / 10, l2 = col - (col / 10) * 10;
      #pragma unroll
      for (int ee = 0; ee < 8; ++ee) {
        const int kk = ch * 8 + ee;
        b2v[ee] = (kk < T) ? dxs[kk * DXP + k2] * dxs[kk * DXP + l2] * 0.5f : 0.f;
      }
    }
    uint4v pk;
    #pragma unroll
    for (int qq = 0; qq < 4; ++qq) pk[qq] = packbf(b2v[2 * qq], b2v[2 * qq + 1]);
    *(uint4v*)&Bb[swz(col, ch * 8)] = pk;
  }
  __syncthreads();

  // ---- GEMM pass 1: A=U2 (from Ub), accumulates; then epilogue ----
  if (w < 7) {
    const int arow = w * 16 + lm;
    short8 a0 = (arow < 100) ? *(const short8*)&Ub[swz(arow, lg * 8)]
                             : short8{0, 0, 0, 0, 0, 0, 0, 0};
    short8 a1 = (arow < 100) ? *(const short8*)&Ub[swz(arow, 32 + lg * 8)]
                             : short8{0, 0, 0, 0, 0, 0, 0, 0};
    #pragma unroll
    for (int ct = 0; ct < 7; ++ct) {
      const int bcol = ct * 16 + lm;
      short8 b0 = (bcol < 110) ? *(const short8*)&Bb[swz(bcol, lg * 8)]
                               : short8{0, 0, 0, 0, 0, 0, 0, 0};
      short8 b1 = (bcol < 110) ? *(const short8*)&Bb[swz(bcol, 32 + lg * 8)]
                               : short8{0, 0, 0, 0, 0, 0, 0, 0};
      acc[ct] = __builtin_amdgcn_mfma_f32_16x16x32_bf16(b0, a0, acc[ct], 0, 0, 0);
      acc[ct] = __builtin_amdgcn_mfma_f32_16x16x32_bf16(b1, a1, acc[ct], 0, 0, 0);
    }

    const int row = w * 16 + lm;           // output ij-row
    if (row < 100) {
      float* rowp4 = ob + 1110 + row * 100;
      float* rowp3 = ob + 110 + row * 10;
      #pragma unroll
      for (int ct = 0; ct < 7; ++ct) {
        const int colbase = ct * 16 + lg * 4;   // 4 consecutive output cols
        f2 lo = {acc[ct][0], acc[ct][1]};
        f2 hi = {acc[ct][2], acc[ct][3]};
        if (colbase < 100) {
          *(f2*)(rowp4 + colbase) = lo;
          *(f2*)(rowp4 + colbase + 2) = hi;
        } else if (colbase < 110) {
          *(f2*)(rowp3 + (colbase - 100)) = lo;
          if (colbase < 108) *(f2*)(rowp3 + (colbase - 98)) = hi;
        }
      }
    }
  }
}

extern "C" void kernel_launch(void* const* d_in, const int* in_sizes, int n_in,
                              void* d_out, int out_size, void* d_ws, size_t ws_size,
                              hipStream_t stream) {
  const float* x = (const float*)d_in[0];
  float* out = (float*)d_out;
  const int batch = in_sizes[0] / (C * L);   // 2048
  sig4_kernel<<<dim3(batch), dim3(512), 0, stream>>>(x, out);
}

// Round 22
// 33.827 us; speedup vs baseline: 1.1176x; 1.1176x over previous
//
#include <hip/hip_runtime.h>
#include <hip/hip_bf16.h>

// Depth-4 path signature, C=10, L=64, B=2048 — MFMA formulation (R22).
// Closed form (validated R8-R21, absmax 5.25 vs thr 12.16):
//   P_t = exclusive prefix of dx;  R_t[l] = S1[l] - P_{t+1}[l]
//   per (i,j): s2 serial chain; u2_t, v2_t level-2 scalars
//   S4[ij,kl] = sum_t v2_t*(dx_t[k]*R_t[l]) + sum_t u2_t*(dx_t[k]*dx_t[l]/2)
//   S3[ij,k]  = sum_t v2_t*dx_t[k]
// Structure = R20 (best, 35.9us): 512thr/1elem/8waves, V2->Ab U2->Ub B->Bb,
// two K=64 GEMM passes (1 rt-strip per wave), transposed-C f2 epilogue.
// R22 delta: TRANSPOSED staging (dxT[c][s], PsT[c][s], SP=68) so every
// build loop reads consecutive-s runs as ds_read_b128 (6 f4 loads/chunk vs
// 24 scalar b32) — R21 proved builds are LDS-instruction-bound. SP=68:
// rows 16B-aligned, 4c mod 32 bank offsets -> <=2-way (free). Slot s=63
// zero-filled; A slot 63 may hold bf16(s2) but B slot 63 == 0 always, so
// the k=63 product vanishes. s2 chain / GEMM / epilogue identical to R20.

typedef short short8 __attribute__((ext_vector_type(8)));
typedef float f2 __attribute__((ext_vector_type(2)));
typedef float f4 __attribute__((ext_vector_type(4)));
typedef float f32x4 __attribute__((ext_vector_type(4)));
typedef unsigned int uint4v __attribute__((ext_vector_type(4)));

constexpr int C = 10, L = 64, T = 63;          // T = L-1 steps
constexpr int OUTSZ = 10 + 100 + 1000 + 10000; // 11110
constexpr int SP = 68;                         // dxT/PsT row stride (fp32, 16B-mult)
constexpr int KS = 64;                         // A/B row stride in shorts (128B)

__device__ __forceinline__ unsigned packbf(float lo, float hi) {  // v_cvt_pk_bf16_f32
  union { __hip_bfloat162 h; unsigned u; } cv;
  cv.h = __float22bfloat162_rn(make_float2(lo, hi));
  return cv.u;
}
__device__ __forceinline__ int swz(int row, int k) {  // short idx, 16B-granule XOR
  return row * KS + ((((k >> 3) ^ (row & 7)) << 3) | (k & 7));
}

__global__ __launch_bounds__(512, 6) void sig4_kernel(
    const float* __restrict__ x, float* __restrict__ out)
{
  __shared__ __align__(16) unsigned char smem_raw[45120];
  unsigned short* Ab = (unsigned short*)smem_raw;            // V2: 12800B
  unsigned short* Ub = (unsigned short*)(smem_raw + 12800);  // U2: 12800B
  unsigned short* Bb = (unsigned short*)(smem_raw + 25600);  // 14080B
  float* dxT = (float*)(smem_raw + 39680);                   // 10*68 f = 2720B
  float* PsT = (float*)(smem_raw + 42400);                   // 10*68 f = 2720B

  const int t = threadIdx.x;
  const int w = t >> 6, lane = t & 63;
  const float* __restrict__ xb = x + (size_t)blockIdx.x * (C * L);
  float* __restrict__ ob = out + (size_t)blockIdx.x * OUTSZ;

  // ---- phase A: dxT (transposed, zero-padded) from global ----
  for (int i = t; i < C * SP; i += 512) {
    int c = i / SP, s = i - c * SP;
    float v = 0.f;
    if (s < T) v = xb[c * L + s + 1] - xb[c * L + s];
    dxT[i] = v;
  }
  __syncthreads();
  // exclusive prefix P per channel (one channel per wave); PsT[c][63] = S1[c]
  for (int c = w; c < C; c += 8) {
    float v = (lane > 0) ? dxT[c * SP + lane - 1] : 0.f;
    #pragma unroll
    for (int d = 1; d < 64; d <<= 1) {
      float y = __shfl_up(v, d);
      if (lane >= d) v += y;
    }
    PsT[c * SP + lane] = v;
  }
  if (t < 40) PsT[(t >> 2) * SP + 64 + (t & 3)] = 0.f;  // zero pad cols 64..67
  __syncthreads();

  // ---- build: A-chain (t<100) -> Ab,Ub || B0 (t>=128) ----
  if (t < 100) {
    const int i_ = t / 10, j_ = t - (t / 10) * 10;
    const float* dip = dxT + i_ * SP;
    const float* pp  = PsT + i_ * SP;
    const float* djp = dxT + j_ * SP;
    float s2 = 0.f;
    #pragma unroll
    for (int ch = 0; ch < 8; ++ch) {
      f4 d0 = *(const f4*)(dip + ch * 8), d1 = *(const f4*)(dip + ch * 8 + 4);
      f4 p0 = *(const f4*)(pp  + ch * 8), p1 = *(const f4*)(pp  + ch * 8 + 4);
      f4 e0 = *(const f4*)(djp + ch * 8), e1 = *(const f4*)(djp + ch * 8 + 4);
      float di[8] = {d0.x, d0.y, d0.z, d0.w, d1.x, d1.y, d1.z, d1.w};
      float pv[8] = {p0.x, p0.y, p0.z, p0.w, p1.x, p1.y, p1.z, p1.w};
      float dj[8] = {e0.x, e0.y, e0.z, e0.w, e1.x, e1.y, e1.z, e1.w};
      float bu[8], bv[8], zz[8];
      #pragma unroll
      for (int e = 0; e < 8; ++e) {            // pointwise (s=63: all zero)
        bu[e] = fmaf(di[e], 0.25f, pv[e]) * (dj[e] * (1.f / 3.f));
        bv[e] = fmaf(di[e], (1.f / 3.f), pv[e]) * (dj[e] * 0.5f);
        zz[e] = fmaf(di[e], 0.5f, pv[e]) * dj[e];
      }
      float u2v[8], v2v[8];
      #pragma unroll
      for (int e = 0; e < 8; ++e) {            // serial: 1 dependent add/step
        u2v[e] = bu[e] + s2;
        v2v[e] = bv[e] + s2;
        s2 += zz[e];
      }
      uint4v vp, up;
      #pragma unroll
      for (int q = 0; q < 4; ++q) {
        vp[q] = packbf(v2v[2 * q], v2v[2 * q + 1]);
        up[q] = packbf(u2v[2 * q], u2v[2 * q + 1]);
      }
      *(uint4v*)&Ab[swz(t, ch * 8)] = vp;
      *(uint4v*)&Ub[swz(t, ch * 8)] = up;
    }
    ob[10 + t] = s2;                           // S2 (fp32)
    if (j_ == 0) ob[i_] = PsT[i_ * SP + 63];   // S1
  } else if (t >= 128) {
    const int q = t - 128;                     // 384 lanes
    for (int task = q; task < 110 * 8; task += 384) {
      const int col = task >> 3, ch = task & 7;
      const int base = ch * 8;
      float b1v[8];
      if (col < 100) {
        const int k2 = col / 10, l2 = col - (col / 10) * 10;
        const float* dk = dxT + k2 * SP;
        const float* pl = PsT + l2 * SP;
        const float S1l = pl[63];
        f4 d0 = *(const f4*)(dk + base), d1 = *(const f4*)(dk + base + 4);
        f4 pa = *(const f4*)(pl + base), pb = *(const f4*)(pl + base + 4);
        f4 pc = *(const f4*)(pl + base + 8);   // pad cols zeroed, safe
        float dv[8] = {d0.x, d0.y, d0.z, d0.w, d1.x, d1.y, d1.z, d1.w};
        float Pn[8] = {pa.y, pa.z, pa.w, pb.x, pb.y, pb.z, pb.w, pc.x};
        #pragma unroll
        for (int e = 0; e < 8; ++e) b1v[e] = dv[e] * (S1l - Pn[e]);
      } else {
        const float* dk = dxT + (col - 100) * SP;
        f4 d0 = *(const f4*)(dk + base), d1 = *(const f4*)(dk + base + 4);
        b1v[0] = d0.x; b1v[1] = d0.y; b1v[2] = d0.z; b1v[3] = d0.w;
        b1v[4] = d1.x; b1v[5] = d1.y; b1v[6] = d1.z; b1v[7] = d1.w;
      }
      uint4v pk;
      #pragma unroll
      for (int qq = 0; qq < 4; ++qq) pk[qq] = packbf(b1v[2 * qq], b1v[2 * qq + 1]);
      *(uint4v*)&Bb[swz(col, base)] = pk;
    }
  }
  __syncthreads();

  const int lm = lane & 15, lg = lane >> 4;
  f32x4 acc[7];
  #pragma unroll
  for (int ct = 0; ct < 7; ++ct) acc[ct] = f32x4{0.f, 0.f, 0.f, 0.f};

  // ---- GEMM pass 0: one rt-strip per wave (waves 0..6), A=V2 ----
  if (w < 7) {
    const int arow = w * 16 + lm;
    short8 a0 = (arow < 100) ? *(const short8*)&Ab[swz(arow, lg * 8)]
                             : short8{0, 0, 0, 0, 0, 0, 0, 0};
    short8 a1 = (arow < 100) ? *(const short8*)&Ab[swz(arow, 32 + lg * 8)]
                             : short8{0, 0, 0, 0, 0, 0, 0, 0};
    #pragma unroll
    for (int ct = 0; ct < 7; ++ct) {
      const int bcol = ct * 16 + lm;
      short8 b0 = (bcol < 110) ? *(const short8*)&Bb[swz(bcol, lg * 8)]
                               : short8{0, 0, 0, 0, 0, 0, 0, 0};
      short8 b1 = (bcol < 110) ? *(const short8*)&Bb[swz(bcol, 32 + lg * 8)]
                               : short8{0, 0, 0, 0, 0, 0, 0, 0};
      acc[ct] = __builtin_amdgcn_mfma_f32_16x16x32_bf16(b0, a0, acc[ct], 0, 0, 0);
      acc[ct] = __builtin_amdgcn_mfma_f32_16x16x32_bf16(b1, a1, acc[ct], 0, 0, 0);
    }
  }
  __syncthreads();

  // ---- build B1 = [dx ox dx /2 | 0] on ALL 512 lanes ----
  for (int task = t; task < 110 * 8; task += 512) {
    const int col = task >> 3, ch = task & 7;
    const int base = ch * 8;
    float b2v[8] = {0.f, 0.f, 0.f, 0.f, 0.f, 0.f, 0.f, 0.f};
    if (col < 100) {
      const int k2 = col / 10, l2 = col - (col / 10) * 10;
      const float* dk = dxT + k2 * SP;
      const float* dl = dxT + l2 * SP;
      f4 a0 = *(const f4*)(dk + base), a1 = *(const f4*)(dk + base + 4);
      f4 c0 = *(const f4*)(dl + base), c1 = *(const f4*)(dl + base + 4);
      b2v[0] = a0.x * c0.x * 0.5f; b2v[1] = a0.y * c0.y * 0.5f;
      b2v[2] = a0.z * c0.z * 0.5f; b2v[3] = a0.w * c0.w * 0.5f;
      b2v[4] = a1.x * c1.x * 0.5f; b2v[5] = a1.y * c1.y * 0.5f;
      b2v[6] = a1.z * c1.z * 0.5f; b2v[7] = a1.w * c1.w * 0.5f;
    }
    uint4v pk;
    #pragma unroll
    for (int qq = 0; qq < 4; ++qq) pk[qq] = packbf(b2v[2 * qq], b2v[2 * qq + 1]);
    *(uint4v*)&Bb[swz(col, base)] = pk;
  }
  __syncthreads();

  // ---- GEMM pass 1: A=U2 (from Ub), accumulates; then epilogue ----
  if (w < 7) {
    const int arow = w * 16 + lm;
    short8 a0 = (arow < 100) ? *(const short8*)&Ub[swz(arow, lg * 8)]
                             : short8{0, 0, 0, 0, 0, 0, 0, 0};
    short8 a1 = (arow < 100) ? *(const short8*)&Ub[swz(arow, 32 + lg * 8)]
                             : short8{0, 0, 0, 0, 0, 0, 0, 0};
    #pragma unroll
    for (int ct = 0; ct < 7; ++ct) {
      const int bcol = ct * 16 + lm;
      short8 b0 = (bcol < 110) ? *(const short8*)&Bb[swz(bcol, lg * 8)]
                               : short8{0, 0, 0, 0, 0, 0, 0, 0};
      short8 b1 = (bcol < 110) ? *(const short8*)&Bb[swz(bcol, 32 + lg * 8)]
                               : short8{0, 0, 0, 0, 0, 0, 0, 0};
      acc[ct] = __builtin_amdgcn_mfma_f32_16x16x32_bf16(b0, a0, acc[ct], 0, 0, 0);
      acc[ct] = __builtin_amdgcn_mfma_f32_16x16x32_bf16(b1, a1, acc[ct], 0, 0, 0);
    }

    const int row = w * 16 + lm;           // output ij-row
    if (row < 100) {
      float* rowp4 = ob + 1110 + row * 100;
      float* rowp3 = ob + 110 + row * 10;
      #pragma unroll
      for (int ct = 0; ct < 7; ++ct) {
        const int colbase = ct * 16 + lg * 4;   // 4 consecutive output cols
        f2 lo = {acc[ct][0], acc[ct][1]};
        f2 hi = {acc[ct][2], acc[ct][3]};
        if (colbase < 100) {
          *(f2*)(rowp4 + colbase) = lo;
          *(f2*)(rowp4 + colbase + 2) = hi;
        } else if (colbase < 110) {
          *(f2*)(rowp3 + (colbase - 100)) = lo;
          if (colbase < 108) *(f2*)(rowp3 + (colbase - 98)) = hi;
        }
      }
    }
  }
}

extern "C" void kernel_launch(void* const* d_in, const int* in_sizes, int n_in,
                              void* d_out, int out_size, void* d_ws, size_t ws_size,
                              hipStream_t stream) {
  const float* x = (const float*)d_in[0];
  float* out = (float*)d_out;
  const int batch = in_sizes[0] / (C * L);   // 2048
  sig4_kernel<<<dim3(batch), dim3(512), 0, stream>>>(x, out);
}